// Round 5
// baseline (359.249 us; speedup 1.0000x reference)
//
#include <hip/hip_runtime.h>

#define I_DIM 17
#define H_DIM 128
#define T_DIM 19
#define B_DIM 32768
#define M_ROWS 64
#define NTHR 1024
#define GRID (B_DIM / M_ROWS) /* 512 */
#define XI 323                /* T*I */
#define NF (M_ROWS * XI)      /* 20672 flat floats per block (x and out) */
#define SLOT 4352             /* per-t XY slot: x-frag 4096, y fp32 4352 */

#define OFF_WIF 0
#define OFF_WOF 32768
#define OFF_H   40960         /* 2 x 16384 */
#define OFF_XY  73728         /* 19 x 4352 = 82688 */
#define LDS_TOT 156416

typedef __bf16 bf16x8 __attribute__((ext_vector_type(8)));
typedef float f32x4 __attribute__((ext_vector_type(4)));
union FragU { bf16x8 v; unsigned short s[8]; uint4 u; };

#define K1 1.4426950408889634f
#define K2 2.8853900817779268f

__device__ __forceinline__ unsigned short f2bf(float f) {
    union { float f; unsigned u; } x; x.f = f;
    return (unsigned short)((x.u + 0x8000u) >> 16);
}

// one timestep; T_ runtime t, P_ compile-time parity (H-buffer select)
#define STEP(T_, P_) do {                                                         \
    /* gates: acc[mtl][g]; A: x-frag + h-frags; B: wih (LDS) + whh (regs) */      \
    f32x4 acc[2][4];                                                              \
    _Pragma("unroll") for (int mtl = 0; mtl < 2; ++mtl)                           \
        _Pragma("unroll") for (int g = 0; g < 4; ++g)                             \
            acc[mtl][g] = (f32x4){bias[g], bias[g], bias[g], bias[g]};            \
    _Pragma("unroll") for (int mtl = 0; mtl < 2; ++mtl) {                         \
        bf16x8 a = *(const bf16x8*)(smem + xyA + mtl * 1024);                     \
        _Pragma("unroll") for (int g = 0; g < 4; ++g) {                           \
            bf16x8 b = *(const bf16x8*)(smem + vwi + g * 1024);                   \
            acc[mtl][g] = __builtin_amdgcn_mfma_f32_16x16x32_bf16(a, b, acc[mtl][g], 0, 0, 0); \
        }                                                                         \
    }                                                                             \
    _Pragma("unroll") for (int kk = 0; kk < 4; ++kk)                              \
        _Pragma("unroll") for (int mtl = 0; mtl < 2; ++mtl) {                     \
            bf16x8 a = *(const bf16x8*)(smem + vkk[kk] + (OFF_H + (1-(P_))*16384 + mtl*4096)); \
            _Pragma("unroll") for (int g = 0; g < 4; ++g)                         \
                acc[mtl][g] = __builtin_amdgcn_mfma_f32_16x16x32_bf16(a, whh[kk][g], acc[mtl][g], 0, 0, 0); \
        }                                                                         \
    /* y_{t-1} = h_{t-1} @ W_out^T  (waves 0..7), into XY slot t-1 */             \
    if ((T_) > 0 && w < 8) {                                                      \
        f32x4 ya = {0.f, 0.f, 0.f, 0.f};                                          \
        _Pragma("unroll") for (int kk = 0; kk < 4; ++kk) {                        \
            bf16x8 a = *(const bf16x8*)(smem + yv[kk] + (OFF_H + (1-(P_))*16384));\
            bf16x8 b = *(const bf16x8*)(smem + vwo + kk * 1024);                  \
            ya = __builtin_amdgcn_mfma_f32_16x16x32_bf16(a, b, ya, 0, 0, 0);      \
        }                                                                         \
        if (yok) {                                                                \
            _Pragma("unroll") for (int r = 0; r < 4; ++r)                         \
                *(float*)(smem + ywb + r * 68) = ya[r] + ybo;                     \
        }                                                                         \
    }                                                                             \
    /* elementwise cell update (5 exp2 + 2 rcp), h_t -> H[P_] */                  \
    _Pragma("unroll") for (int mtl = 0; mtl < 2; ++mtl)                           \
        _Pragma("unroll") for (int r = 0; r < 4; ++r) {                           \
            float ig = acc[mtl][0][r], fg = acc[mtl][1][r];                       \
            float gg = acc[mtl][2][r], og = acc[mtl][3][r];                       \
            float ui = __builtin_amdgcn_exp2f(-K1 * ig);                          \
            float uf = __builtin_amdgcn_exp2f(-K1 * fg);                          \
            float vg = __builtin_amdgcn_exp2f(-K2 * gg);                          \
            float uo = __builtin_amdgcn_exp2f(-K1 * og);                          \
            float A_ = 1.f + ui, F_ = 1.f + uf, G_ = 1.f + vg;                    \
            float AG = A_ * G_;                                                   \
            float c = (cst[mtl*4+r] * AG + (1.f - vg) * F_) * __builtin_amdgcn_rcpf(F_ * AG); \
            cst[mtl*4+r] = c;                                                     \
            float vc = __builtin_amdgcn_exp2f(-K2 * c);                           \
            float h = (1.f - vc) * __builtin_amdgcn_rcpf((1.f + uo) * (1.f + vc));\
            *(unsigned short*)(smem + vwr[r] + (OFF_H + (P_)*16384 + mtl*4096)) = f2bf(h); \
        }                                                                         \
    xyA += SLOT; ywb += SLOT;                                                     \
    __syncthreads();                                                              \
} while (0)

__global__ __launch_bounds__(NTHR, 4) void flowlstm(
    const float* __restrict__ x, const float* __restrict__ W_ih,
    const float* __restrict__ W_hh, const float* __restrict__ b_ih,
    const float* __restrict__ b_hh, const float* __restrict__ W_out,
    const float* __restrict__ b_out, float* __restrict__ out)
{
    __shared__ __align__(16) unsigned char smem[LDS_TOT];
    const int tid = threadIdx.x;
    const int w = tid >> 6, lane = tid & 63, l15 = lane & 15, q = lane >> 4;
    const int mth = w >> 3, cg = w & 7;   // wave: rows mth*32.., gate-cols g*128+cg*16
    const int b0 = blockIdx.x * M_ROWS;

    // ---- zero XY region (82688 B) + H[1] (h_{-1}=0) ----
    #pragma unroll
    for (int j = 0; j < 21; ++j) {
        int f = tid + j * NTHR;
        if (j < 20 || tid < (NF - 20 * NTHR))
            *(unsigned*)(smem + OFF_XY + (unsigned)f * 4) = 0u;
    }
    #pragma unroll
    for (int j = 0; j < 4; ++j)
        *(unsigned*)(smem + OFF_H + 16384 + (unsigned)(tid + j * NTHR) * 4) = 0u;

    // ---- stage W_ih fragments (32 frags, K pad 17->32) ----
    #pragma unroll
    for (int i = 0; i < 2; ++i) {
        int s = tid + i * NTHR;
        int ln = s & 63, f = s >> 6;         // f = cgs*4 + g
        int g = f & 3, cgs = f >> 2;
        int n = g * H_DIM + cgs * 16 + (ln & 15);
        int kb = (ln >> 4) * 8;
        FragU fu;
        #pragma unroll
        for (int e = 0; e < 8; ++e)
            fu.s[e] = (kb + e < I_DIM) ? f2bf(W_ih[n * I_DIM + kb + e]) : (unsigned short)0;
        *(uint4*)(smem + OFF_WIF + f * 1024 + ln * 16) = fu.u;
    }
    // ---- stage W_out fragments (8 frags: ct*4+kk, N pad 17->32) ----
    if (tid < 512) {
        int ln = tid & 63, f = tid >> 6;
        int kk = f & 3, ct = f >> 2;
        int o = ct * 16 + (ln & 15);
        int kb = kk * 32 + (ln >> 4) * 8;
        FragU fu;
        #pragma unroll
        for (int e = 0; e < 8; ++e)
            fu.s[e] = (o < I_DIM) ? f2bf(W_out[o * H_DIM + kb + e]) : (unsigned short)0;
        *(uint4*)(smem + OFF_WOF + tid * 16) = fu.u;
    }
    // ---- W_hh fragments in registers (16 frags = 64 regs) ----
    bf16x8 whh[4][4];
    #pragma unroll
    for (int kk = 0; kk < 4; ++kk)
        #pragma unroll
        for (int g = 0; g < 4; ++g) {
            int n = g * H_DIM + cg * 16 + l15;
            const float* s = W_hh + n * H_DIM + kk * 32 + q * 8;
            FragU fu;
            #pragma unroll
            for (int e = 0; e < 8; ++e) fu.s[e] = f2bf(s[e]);
            whh[kk][g] = fu.v;
        }
    float bias[4];
    #pragma unroll
    for (int g = 0; g < 4; ++g) {
        int col = g * H_DIM + cg * 16 + l15;
        bias[g] = b_ih[col] + b_hh[col];
    }
    // ---- t-invariant LDS vaddrs ----
    const unsigned xr7 = (unsigned)((l15 & 7) << 4);
    unsigned vkk[4], yv[4], vwr[4];
    #pragma unroll
    for (int kk = 0; kk < 4; ++kk) {
        vkk[kk] = (unsigned)(mth * 8192 + l15 * 256 + ((kk * 64 + q * 16) ^ xr7));
        yv[kk]  = (unsigned)((w >> 1) * 4096 + l15 * 256 + ((kk * 64 + q * 16) ^ xr7));
    }
    const int colh2 = (cg * 16 + l15) * 2;
    #pragma unroll
    for (int r = 0; r < 4; ++r) {
        int rq = q * 4 + r;
        vwr[r] = (unsigned)(mth * 8192 + rq * 256 + (colh2 ^ ((rq & 7) << 4)));
    }
    const unsigned vwi = (unsigned)(OFF_WIF + cg * 4096 + lane * 16);
    const int yct = w & 1;
    const unsigned vwo = (unsigned)(OFF_WOF + yct * 4096 + lane * 16);
    const int ycol = yct * 16 + l15;
    const bool yok = (ycol < I_DIM);
    const float ybo = b_out[ycol < I_DIM ? ycol : 16];
    unsigned xyA = (unsigned)(OFF_XY + mth * 2048 + (q * 16 + l15) * 16);
    unsigned ywb = (unsigned)(OFF_XY - SLOT + ((w >> 1) * 16 + q * 4) * 68 + ycol * 4);

    // ---- bulk x load: coalesced dwords -> bf16 scatter into frag layout ----
    {
        const float* xb = x + (size_t)b0 * XI;
        #pragma unroll
        for (int j = 0; j < 21; ++j) {
            int f = tid + j * NTHR;
            if (j < 20 || tid < (NF - 20 * NTHR)) {
                float v = xb[f];
                unsigned row = ((unsigned)f * 51943u) >> 24;       // f / 323
                unsigned s = (unsigned)f - row * 323u;
                unsigned t = (s * 61681u) >> 20;                   // s / 17
                unsigned k = s - t * 17u;
                unsigned a = OFF_XY + t * SLOT + (row >> 4) * 1024
                           + (((k >> 3) * 16 + (row & 15)) * 16) + (k & 7) * 2;
                *(unsigned short*)(smem + a) = f2bf(v);
            }
        }
    }
    float cst[8];
    #pragma unroll
    for (int i = 0; i < 8; ++i) cst[i] = 0.f;

    __syncthreads();   // all staging + zeros visible

    #pragma unroll 1
    for (int t = 0; t < T_DIM - 1; t += 2) {
        STEP(t, 0);
        STEP(t + 1, 1);
    }
    STEP(T_DIM - 1, 0);   // t = 18, writes H[0]

    // ---- epilogue: y_18 from H[0] into slot 18 ----
    if (w < 8) {
        f32x4 ya = {0.f, 0.f, 0.f, 0.f};
        #pragma unroll
        for (int kk = 0; kk < 4; ++kk) {
            bf16x8 a = *(const bf16x8*)(smem + yv[kk] + OFF_H);
            bf16x8 b = *(const bf16x8*)(smem + vwo + kk * 1024);
            ya = __builtin_amdgcn_mfma_f32_16x16x32_bf16(a, b, ya, 0, 0, 0);
        }
        if (yok) {
            #pragma unroll
            for (int r = 0; r < 4; ++r)
                *(float*)(smem + ywb + r * 68) = ya[r] + ybo;
        }
    }
    __syncthreads();

    // ---- coalesced flush: LDS y slots -> contiguous out range ----
    {
        float* ob = out + (size_t)b0 * XI;
        #pragma unroll
        for (int j = 0; j < 21; ++j) {
            int f = tid + j * NTHR;
            if (j < 20 || tid < (NF - 20 * NTHR)) {
                unsigned row = ((unsigned)f * 51943u) >> 24;
                unsigned s = (unsigned)f - row * 323u;
                unsigned t = (s * 61681u) >> 20;
                unsigned col = s - t * 17u;
                ob[f] = *(const float*)(smem + OFF_XY + t * SLOT + row * 68 + col * 4);
            }
        }
    }
}

extern "C" void kernel_launch(void* const* d_in, const int* in_sizes, int n_in,
                              void* d_out, int out_size, void* d_ws, size_t ws_size,
                              hipStream_t stream) {
    const float* x     = (const float*)d_in[0];
    const float* W_ih  = (const float*)d_in[1];
    const float* W_hh  = (const float*)d_in[2];
    const float* b_ih  = (const float*)d_in[3];
    const float* b_hh  = (const float*)d_in[4];
    const float* W_out = (const float*)d_in[5];
    const float* b_out = (const float*)d_in[6];
    float* out = (float*)d_out;

    dim3 grid(GRID), block(NTHR);
    flowlstm<<<grid, block, 0, stream>>>(x, W_ih, W_hh, b_ih, b_hh, W_out, b_out, out);
}

// Round 6
// 224.833 us; speedup vs baseline: 1.5978x; 1.5978x over previous
//
#include <hip/hip_runtime.h>

#define I_DIM 17
#define H_DIM 128
#define T_DIM 19
#define B_DIM 32768
#define M_ROWS 64
#define NTHR 512
#define GRID (B_DIM / M_ROWS) /* 512 */
#define XI 323                /* T*I */
#define NF (M_ROWS * XI)      /* 20672 floats per block */
#define SLOT 4352             /* per-t XY slot: x-frag 4096, y fp32 64*68 */

/* LDS layout — H first so all H imm offsets stay < 32K (16-bit ds imm) */
#define OFF_H   0             /* 2 x 16384 */
#define OFF_WIF 32768         /* 32 frags x 1024 */
#define OFF_WOF 65536         /* 8 frags x 1024 */
#define OFF_XY  73728         /* 19 x 4352 = 82688 */
#define LDS_TOT 156416

typedef __bf16 bf16x8 __attribute__((ext_vector_type(8)));
typedef float f32x4 __attribute__((ext_vector_type(4)));
union FragU { bf16x8 v; unsigned short s[8]; uint4 u; };

#define K1 1.4426950408889634f
#define K2 2.8853900817779268f

__device__ __forceinline__ unsigned short f2bf(float f) {
    union { float f; unsigned u; } x; x.f = f;
    return (unsigned short)((x.u + 0x8000u) >> 16);
}

// one timestep; T_ runtime t, P_ compile-time parity (H-buffer select)
#define STEP(T_, P_) do {                                                         \
    f32x4 acc[4][4];                                                              \
    _Pragma("unroll") for (int mtl = 0; mtl < 4; ++mtl)                           \
        _Pragma("unroll") for (int g = 0; g < 4; ++g)                             \
            acc[mtl][g] = (f32x4){bias[g], bias[g], bias[g], bias[g]};            \
    /* x-projection (K=32 zero-padded) */                                         \
    _Pragma("unroll") for (int mtl = 0; mtl < 4; ++mtl) {                         \
        bf16x8 a = *(const bf16x8*)(smem + xyA + mtl * 1024);                     \
        _Pragma("unroll") for (int g = 0; g < 4; ++g) {                           \
            bf16x8 b = *(const bf16x8*)(smem + vwi + g * 1024);                   \
            acc[mtl][g] = __builtin_amdgcn_mfma_f32_16x16x32_bf16(a, b, acc[mtl][g], 0, 0, 0); \
        }                                                                         \
    }                                                                             \
    /* recurrent: h_{t-1} @ W_hh^T (B-frags in registers) */                      \
    _Pragma("unroll") for (int kk = 0; kk < 4; ++kk)                              \
        _Pragma("unroll") for (int mtl = 0; mtl < 4; ++mtl) {                     \
            bf16x8 a = *(const bf16x8*)(smem + vkk[kk] + ((1-(P_))*16384 + mtl*4096)); \
            _Pragma("unroll") for (int g = 0; g < 4; ++g)                         \
                acc[mtl][g] = __builtin_amdgcn_mfma_f32_16x16x32_bf16(a, whh[kk][g], acc[mtl][g], 0, 0, 0); \
        }                                                                         \
    /* y_{t-1} = h_{t-1} @ W_out^T, into XY slot t-1 */                           \
    if ((T_) > 0) {                                                               \
        f32x4 ya = {0.f, 0.f, 0.f, 0.f};                                          \
        _Pragma("unroll") for (int kk = 0; kk < 4; ++kk) {                        \
            bf16x8 a = *(const bf16x8*)(smem + vkk[kk] + ymt4 + (1-(P_))*16384);  \
            bf16x8 b = *(const bf16x8*)(smem + vwo + kk * 1024);                  \
            ya = __builtin_amdgcn_mfma_f32_16x16x32_bf16(a, b, ya, 0, 0, 0);      \
        }                                                                         \
        if (yok) {                                                                \
            _Pragma("unroll") for (int r = 0; r < 4; ++r)                         \
                *(float*)(smem + ywb + r * 68) = ya[r] + ybo;                     \
        }                                                                         \
    }                                                                             \
    /* elementwise cell update (5 exp2 + 2 rcp), h_t -> H[P_] */                  \
    _Pragma("unroll") for (int mtl = 0; mtl < 4; ++mtl)                           \
        _Pragma("unroll") for (int r = 0; r < 4; ++r) {                           \
            float ig = acc[mtl][0][r], fg = acc[mtl][1][r];                       \
            float gg = acc[mtl][2][r], og = acc[mtl][3][r];                       \
            float ui = __builtin_amdgcn_exp2f(-K1 * ig);                          \
            float uf = __builtin_amdgcn_exp2f(-K1 * fg);                          \
            float vg = __builtin_amdgcn_exp2f(-K2 * gg);                          \
            float uo = __builtin_amdgcn_exp2f(-K1 * og);                          \
            float A_ = 1.f + ui, F_ = 1.f + uf, G_ = 1.f + vg;                    \
            float AG = A_ * G_;                                                   \
            float c = (cst[mtl*4+r] * AG + (1.f - vg) * F_) * __builtin_amdgcn_rcpf(F_ * AG); \
            cst[mtl*4+r] = c;                                                     \
            float vc = __builtin_amdgcn_exp2f(-K2 * c);                           \
            float h = (1.f - vc) * __builtin_amdgcn_rcpf((1.f + uo) * (1.f + vc));\
            *(unsigned short*)(smem + vwr[r] + ((P_)*16384 + mtl*4096)) = f2bf(h);\
        }                                                                         \
    xyA += SLOT; ywb += SLOT;                                                     \
    __syncthreads();                                                              \
} while (0)

__global__ __launch_bounds__(NTHR, 2) void flowlstm(
    const float* __restrict__ x, const float* __restrict__ W_ih,
    const float* __restrict__ W_hh, const float* __restrict__ b_ih,
    const float* __restrict__ b_hh, const float* __restrict__ W_out,
    const float* __restrict__ b_out, float* __restrict__ out)
{
    __shared__ __align__(16) unsigned char smem[LDS_TOT];
    const int tid = threadIdx.x;
    const int w = tid >> 6, lane = tid & 63, l15 = lane & 15, q = lane >> 4;
    const int cg = w;                      // wave owns gate-cols g*128 + cg*16 + l15
    const int b0 = blockIdx.x * M_ROWS;

    // ---- zero H[1] (h_{-1}=0): 4096 dwords ----
    #pragma unroll
    for (int j = 0; j < 8; ++j)
        *(unsigned*)(smem + 16384 + (unsigned)(tid + j * NTHR) * 4) = 0u;
    // ---- zero kgroup-3 quarter of every x-frag chunk (K-pad 24..31) ----
    for (int d = tid; d < 4864; d += NTHR) {
        int slot = d >> 8, within = d & 255, chunk = within >> 6, dw = within & 63;
        *(unsigned*)(smem + OFF_XY + slot * SLOT + chunk * 1024 + 768 + dw * 4) = 0u;
    }
    // ---- stage W_ih fragments (32 frags, K pad 17->32) ----
    #pragma unroll
    for (int i = 0; i < 4; ++i) {
        int s = tid + i * NTHR;
        int ln = s & 63, f = s >> 6;         // f = cgs*4 + g
        int g = f & 3, cgs = f >> 2;
        int n = g * H_DIM + cgs * 16 + (ln & 15);
        int kb = (ln >> 4) * 8;
        FragU fu;
        #pragma unroll
        for (int e = 0; e < 8; ++e)
            fu.s[e] = (kb + e < I_DIM) ? f2bf(W_ih[n * I_DIM + kb + e]) : (unsigned short)0;
        *(uint4*)(smem + OFF_WIF + f * 1024 + ln * 16) = fu.u;
    }
    // ---- stage W_out fragments (8 frags = ct*4+kk, N pad 17->32) ----
    {
        int ln = tid & 63, f = tid >> 6;
        int kk = f & 3, ct = f >> 2;
        int o = ct * 16 + (ln & 15);
        int kb = kk * 32 + (ln >> 4) * 8;
        FragU fu;
        #pragma unroll
        for (int e = 0; e < 8; ++e)
            fu.s[e] = (o < I_DIM) ? f2bf(W_out[o * H_DIM + kb + e]) : (unsigned short)0;
        *(uint4*)(smem + OFF_WOF + tid * 16) = fu.u;
    }
    // ---- W_hh fragments in registers (16 frags = 64 regs) ----
    bf16x8 whh[4][4];
    #pragma unroll
    for (int kk = 0; kk < 4; ++kk)
        #pragma unroll
        for (int g = 0; g < 4; ++g) {
            int n = g * H_DIM + cg * 16 + l15;
            const float* s = W_hh + n * H_DIM + kk * 32 + q * 8;
            FragU fu;
            #pragma unroll
            for (int e = 0; e < 8; ++e) fu.s[e] = f2bf(s[e]);
            whh[kk][g] = fu.v;
        }
    float bias[4];
    #pragma unroll
    for (int g = 0; g < 4; ++g) {
        int col = g * H_DIM + cg * 16 + l15;
        bias[g] = b_ih[col] + b_hh[col];
    }
    // ---- t-invariant LDS vaddrs ----
    const unsigned xr7 = (unsigned)((l15 & 7) << 4);
    unsigned vkk[4], vwr[4];
    #pragma unroll
    for (int kk = 0; kk < 4; ++kk)
        vkk[kk] = (unsigned)(l15 * 256 + ((kk * 64 + q * 16) ^ xr7));
    const int colh2 = (cg * 16 + l15) * 2;
    #pragma unroll
    for (int r = 0; r < 4; ++r) {
        int rq = q * 4 + r;
        vwr[r] = (unsigned)(rq * 256 + (colh2 ^ ((rq & 7) << 4)));
    }
    const unsigned vwi = (unsigned)(OFF_WIF + cg * 4096 + lane * 16);
    const int ymt = w >> 1, yct = w & 1;
    const unsigned ymt4 = (unsigned)(ymt * 4096);
    const unsigned vwo = (unsigned)(OFF_WOF + yct * 4096 + lane * 16);
    const int ycol = yct * 16 + l15;
    const bool yok = (ycol < I_DIM);
    const float ybo = b_out[ycol < I_DIM ? ycol : 16];
    unsigned xyA = (unsigned)(OFF_XY + q * 256 + l15 * 16);
    unsigned ywb = (unsigned)(OFF_XY - SLOT + (ymt * 16 + q * 4) * 68 + ycol * 4);

    // ---- bulk x load: coalesced dwords -> bf16 scatter into frag layout ----
    {
        const float* xb = x + (size_t)b0 * XI;
        #pragma unroll
        for (int j = 0; j < 41; ++j) {
            int f = tid + j * NTHR;
            if (j < 40 || tid < (NF - 40 * NTHR)) {
                float v = xb[f];
                unsigned row = ((unsigned)f * 51943u) >> 24;       // f / 323
                unsigned s = (unsigned)f - row * 323u;
                unsigned t = (s * 61681u) >> 20;                   // s / 17
                unsigned k = s - t * 17u;
                unsigned base = OFF_XY + t * SLOT + (row >> 4) * 1024;
                if (k == 16) {       // writes full 16-B line: value + K-pad 17..23
                    FragU fu; fu.u = (uint4){0u, 0u, 0u, 0u};
                    fu.s[0] = f2bf(v);
                    *(uint4*)(smem + base + (32 + (row & 15)) * 16) = fu.u;
                } else {
                    unsigned a = base + (((k >> 3) * 16 + (row & 15)) * 16) + (k & 7) * 2;
                    *(unsigned short*)(smem + a) = f2bf(v);
                }
            }
        }
    }
    float cst[16];
    #pragma unroll
    for (int i = 0; i < 16; ++i) cst[i] = 0.f;

    __syncthreads();   // all staging + zeros visible

    #pragma unroll 1
    for (int t = 0; t < T_DIM - 1; t += 2) {
        STEP(t, 0);
        STEP(t + 1, 1);
    }
    STEP(T_DIM - 1, 0);   // t = 18, writes H[0]

    // ---- epilogue: y_18 from H[0] into slot 18 ----
    {
        f32x4 ya = {0.f, 0.f, 0.f, 0.f};
        #pragma unroll
        for (int kk = 0; kk < 4; ++kk) {
            bf16x8 a = *(const bf16x8*)(smem + vkk[kk] + ymt4);
            bf16x8 b = *(const bf16x8*)(smem + vwo + kk * 1024);
            ya = __builtin_amdgcn_mfma_f32_16x16x32_bf16(a, b, ya, 0, 0, 0);
        }
        if (yok) {
            #pragma unroll
            for (int r = 0; r < 4; ++r)
                *(float*)(smem + ywb + r * 68) = ya[r] + ybo;
        }
    }
    __syncthreads();

    // ---- coalesced flush: LDS y slots -> contiguous out range ----
    {
        float* ob = out + (size_t)b0 * XI;
        #pragma unroll
        for (int j = 0; j < 41; ++j) {
            int f = tid + j * NTHR;
            if (j < 40 || tid < (NF - 40 * NTHR)) {
                unsigned row = ((unsigned)f * 51943u) >> 24;
                unsigned s = (unsigned)f - row * 323u;
                unsigned t = (s * 61681u) >> 20;
                unsigned col = s - t * 17u;
                ob[f] = *(const float*)(smem + OFF_XY + t * SLOT + row * 68 + col * 4);
            }
        }
    }
}

extern "C" void kernel_launch(void* const* d_in, const int* in_sizes, int n_in,
                              void* d_out, int out_size, void* d_ws, size_t ws_size,
                              hipStream_t stream) {
    const float* x     = (const float*)d_in[0];
    const float* W_ih  = (const float*)d_in[1];
    const float* W_hh  = (const float*)d_in[2];
    const float* b_ih  = (const float*)d_in[3];
    const float* b_hh  = (const float*)d_in[4];
    const float* W_out = (const float*)d_in[5];
    const float* b_out = (const float*)d_in[6];
    float* out = (float*)d_out;

    dim3 grid(GRID), block(NTHR);
    flowlstm<<<grid, block, 0, stream>>>(x, W_ih, W_hh, b_ih, b_hh, W_out, b_out, out);
}

// Round 7
// 190.473 us; speedup vs baseline: 1.8861x; 1.1804x over previous
//
#include <hip/hip_runtime.h>

#define I_DIM 17
#define H_DIM 128
#define T_DIM 19
#define B_DIM 32768
#define M_ROWS 64
#define NTHR 512
#define GRID (B_DIM / M_ROWS) /* 512 */
#define XI 323                /* T*I */
#define NF (M_ROWS * XI)      /* 20672 floats per block */
#define SLOT 4352             /* per-t XY slot: x-frag 4096, y fp32 64*68 */

/* LDS: H dbuf first (imm-offset friendly), then XY slots */
#define OFF_H   0             /* 2 x 16384 */
#define OFF_XY  32768         /* 19 x 4352 = 82688 */
#define LDS_TOT 115456

typedef __bf16 bf16x8 __attribute__((ext_vector_type(8)));
typedef float f32x4 __attribute__((ext_vector_type(4)));
union FragU { bf16x8 v; unsigned short s[8]; uint4 u; };

#define K1 1.4426950408889634f
#define K2 2.8853900817779268f

__device__ __forceinline__ unsigned short f2bf(float f) {
    union { float f; unsigned u; } x; x.f = f;
    return (unsigned short)((x.u + 0x8000u) >> 16);
}

// one timestep; T_ runtime t, P_ compile-time parity (H-buffer select)
#define STEP(T_, P_) do {                                                         \
    f32x4 acc[4][4];                                                              \
    _Pragma("unroll") for (int mtl = 0; mtl < 4; ++mtl)                           \
        _Pragma("unroll") for (int g = 0; g < 4; ++g)                             \
            acc[mtl][g] = (f32x4){bias[g], bias[g], bias[g], bias[g]};            \
    /* x-projection (K=32 zero-padded), B-frags in registers */                   \
    _Pragma("unroll") for (int mtl = 0; mtl < 4; ++mtl) {                         \
        bf16x8 a = *(const bf16x8*)(smem + xyA + mtl * 1024);                     \
        _Pragma("unroll") for (int g = 0; g < 4; ++g)                             \
            acc[mtl][g] = __builtin_amdgcn_mfma_f32_16x16x32_bf16(a, wihr[g], acc[mtl][g], 0, 0, 0); \
    }                                                                             \
    /* recurrent: h_{t-1} @ W_hh^T (B-frags in registers) */                      \
    _Pragma("unroll") for (int kk = 0; kk < 4; ++kk)                              \
        _Pragma("unroll") for (int mtl = 0; mtl < 4; ++mtl) {                     \
            bf16x8 a = *(const bf16x8*)(smem + vkk[kk] + ((1-(P_))*16384 + mtl*4096)); \
            _Pragma("unroll") for (int g = 0; g < 4; ++g)                         \
                acc[mtl][g] = __builtin_amdgcn_mfma_f32_16x16x32_bf16(a, whh[kk][g], acc[mtl][g], 0, 0, 0); \
        }                                                                         \
    /* y_{t-1} = h_{t-1} @ W_out^T, into XY slot t-1 */                           \
    if ((T_) > 0) {                                                               \
        f32x4 ya = {0.f, 0.f, 0.f, 0.f};                                          \
        _Pragma("unroll") for (int kk = 0; kk < 4; ++kk) {                        \
            bf16x8 a = *(const bf16x8*)(smem + vkk[kk] + ymt4 + (1-(P_))*16384);  \
            ya = __builtin_amdgcn_mfma_f32_16x16x32_bf16(a, wor[kk], ya, 0, 0, 0);\
        }                                                                         \
        if (yok) {                                                                \
            _Pragma("unroll") for (int r = 0; r < 4; ++r)                         \
                *(float*)(smem + ywb + r * 68) = ya[r] + ybo;                     \
        }                                                                         \
    }                                                                             \
    /* elementwise cell update (5 exp2 + 2 rcp), h_t -> H[P_] */                  \
    _Pragma("unroll") for (int mtl = 0; mtl < 4; ++mtl)                           \
        _Pragma("unroll") for (int r = 0; r < 4; ++r) {                           \
            float ig = acc[mtl][0][r], fg = acc[mtl][1][r];                       \
            float gg = acc[mtl][2][r], og = acc[mtl][3][r];                       \
            float ui = __builtin_amdgcn_exp2f(-K1 * ig);                          \
            float uf = __builtin_amdgcn_exp2f(-K1 * fg);                          \
            float vg = __builtin_amdgcn_exp2f(-K2 * gg);                          \
            float uo = __builtin_amdgcn_exp2f(-K1 * og);                          \
            float A_ = 1.f + ui, F_ = 1.f + uf, G_ = 1.f + vg;                    \
            float AG = A_ * G_;                                                   \
            float c = (cst[mtl*4+r] * AG + (1.f - vg) * F_) * __builtin_amdgcn_rcpf(F_ * AG); \
            cst[mtl*4+r] = c;                                                     \
            float vc = __builtin_amdgcn_exp2f(-K2 * c);                           \
            float h = (1.f - vc) * __builtin_amdgcn_rcpf((1.f + uo) * (1.f + vc));\
            *(unsigned short*)(smem + vwr[r] + ((P_)*16384 + mtl*4096)) = f2bf(h);\
        }                                                                         \
    xyA += SLOT; ywb += SLOT;                                                     \
    __syncthreads();                                                              \
} while (0)

__global__ __launch_bounds__(NTHR)
__attribute__((amdgpu_waves_per_eu(2, 2)))
void flowlstm(
    const float* __restrict__ x, const float* __restrict__ W_ih,
    const float* __restrict__ W_hh, const float* __restrict__ b_ih,
    const float* __restrict__ b_hh, const float* __restrict__ W_out,
    const float* __restrict__ b_out, float* __restrict__ out)
{
    __shared__ __align__(16) unsigned char smem[LDS_TOT];
    const int tid = threadIdx.x;
    const int w = tid >> 6, lane = tid & 63, l15 = lane & 15, q = lane >> 4;
    const int cg = w;                      // wave owns gate-cols g*128 + cg*16 + l15
    const int b0 = blockIdx.x * M_ROWS;

    // ---- zero H[1] (h_{-1}=0): 4096 dwords ----
    #pragma unroll
    for (int j = 0; j < 8; ++j)
        *(unsigned*)(smem + 16384 + (unsigned)(tid + j * NTHR) * 4) = 0u;
    // ---- zero kgroup-3 quarter of every x-frag chunk (K-pad 24..31) ----
    for (int d = tid; d < 4864; d += NTHR) {
        int slot = d >> 8, within = d & 255, chunk = within >> 6, dw = within & 63;
        *(unsigned*)(smem + OFF_XY + slot * SLOT + chunk * 1024 + 768 + dw * 4) = 0u;
    }
    // ---- W_hh fragments in registers (16 frags = 64 regs) ----
    bf16x8 whh[4][4];
    #pragma unroll
    for (int kk = 0; kk < 4; ++kk)
        #pragma unroll
        for (int g = 0; g < 4; ++g) {
            int n = g * H_DIM + cg * 16 + l15;
            const float* s = W_hh + n * H_DIM + kk * 32 + q * 8;
            FragU fu;
            #pragma unroll
            for (int e = 0; e < 8; ++e) fu.s[e] = f2bf(s[e]);
            whh[kk][g] = fu.v;
        }
    // ---- W_ih fragments in registers (4 frags = 16 regs, K pad 17->32) ----
    bf16x8 wihr[4];
    #pragma unroll
    for (int g = 0; g < 4; ++g) {
        int n = g * H_DIM + cg * 16 + l15;
        FragU fu;
        #pragma unroll
        for (int e = 0; e < 8; ++e) {
            int k = q * 8 + e;
            fu.s[e] = (k < I_DIM) ? f2bf(W_ih[n * I_DIM + k]) : (unsigned short)0;
        }
        wihr[g] = fu.v;
    }
    // ---- W_out fragments in registers (4 frags = 16 regs, N pad 17->32) ----
    const int ymt = w >> 1, yct = w & 1;
    const int ycol = yct * 16 + l15;
    bf16x8 wor[4];
    #pragma unroll
    for (int kk = 0; kk < 4; ++kk) {
        FragU fu;
        #pragma unroll
        for (int e = 0; e < 8; ++e)
            fu.s[e] = (ycol < I_DIM) ? f2bf(W_out[ycol * H_DIM + kk * 32 + q * 8 + e])
                                     : (unsigned short)0;
        wor[kk] = fu.v;
    }
    float bias[4];
    #pragma unroll
    for (int g = 0; g < 4; ++g) {
        int col = g * H_DIM + cg * 16 + l15;
        bias[g] = b_ih[col] + b_hh[col];
    }
    // ---- t-invariant LDS vaddrs ----
    const unsigned xr7 = (unsigned)((l15 & 7) << 4);
    unsigned vkk[4], vwr[4];
    #pragma unroll
    for (int kk = 0; kk < 4; ++kk)
        vkk[kk] = (unsigned)(l15 * 256 + ((kk * 64 + q * 16) ^ xr7));
    const int colh2 = (cg * 16 + l15) * 2;
    #pragma unroll
    for (int r = 0; r < 4; ++r) {
        int rq = q * 4 + r;
        vwr[r] = (unsigned)(rq * 256 + (colh2 ^ ((rq & 7) << 4)));
    }
    const unsigned ymt4 = (unsigned)(ymt * 4096);
    const bool yok = (ycol < I_DIM);
    const float ybo = b_out[ycol < I_DIM ? ycol : 16];
    unsigned xyA = (unsigned)(OFF_XY + q * 256 + l15 * 16);
    unsigned ywb = (unsigned)(OFF_XY - SLOT + (ymt * 16 + q * 4) * 68 + ycol * 4);

    // ---- bulk x load: coalesced dwords -> bf16 scatter into frag layout ----
    {
        const float* xb = x + (size_t)b0 * XI;
        #pragma unroll 4
        for (int j = 0; j < 41; ++j) {
            int f = tid + j * NTHR;
            if (f < NF) {
                float v = xb[f];
                unsigned row = ((unsigned)f * 51943u) >> 24;       // f / 323
                unsigned s = (unsigned)f - row * 323u;
                unsigned t = (s * 61681u) >> 20;                   // s / 17
                unsigned k = s - t * 17u;
                unsigned base = OFF_XY + t * SLOT + (row >> 4) * 1024;
                if (k == 16) {       // full 16-B line: value + K-pad 17..23
                    FragU fu; fu.u = (uint4){0u, 0u, 0u, 0u};
                    fu.s[0] = f2bf(v);
                    *(uint4*)(smem + base + (32 + (row & 15)) * 16) = fu.u;
                } else {
                    unsigned a = base + (((k >> 3) * 16 + (row & 15)) * 16) + (k & 7) * 2;
                    *(unsigned short*)(smem + a) = f2bf(v);
                }
            }
        }
    }
    float cst[16];
    #pragma unroll
    for (int i = 0; i < 16; ++i) cst[i] = 0.f;

    __syncthreads();   // all staging + zeros visible

    #pragma unroll 1
    for (int t = 0; t < T_DIM - 1; t += 2) {
        STEP(t, 0);
        STEP(t + 1, 1);
    }
    STEP(T_DIM - 1, 0);   // t = 18, writes H[0]

    // ---- epilogue: y_18 from H[0] into slot 18 ----
    {
        f32x4 ya = {0.f, 0.f, 0.f, 0.f};
        #pragma unroll
        for (int kk = 0; kk < 4; ++kk) {
            bf16x8 a = *(const bf16x8*)(smem + vkk[kk] + ymt4);
            ya = __builtin_amdgcn_mfma_f32_16x16x32_bf16(a, wor[kk], ya, 0, 0, 0);
        }
        if (yok) {
            #pragma unroll
            for (int r = 0; r < 4; ++r)
                *(float*)(smem + ywb + r * 68) = ya[r] + ybo;
        }
    }
    __syncthreads();

    // ---- coalesced flush: LDS y slots -> contiguous out range ----
    {
        float* ob = out + (size_t)b0 * XI;
        #pragma unroll 4
        for (int j = 0; j < 41; ++j) {
            int f = tid + j * NTHR;
            if (f < NF) {
                unsigned row = ((unsigned)f * 51943u) >> 24;
                unsigned s = (unsigned)f - row * 323u;
                unsigned t = (s * 61681u) >> 20;
                unsigned col = s - t * 17u;
                ob[f] = *(const float*)(smem + OFF_XY + t * SLOT + row * 68 + col * 4);
            }
        }
    }
}

extern "C" void kernel_launch(void* const* d_in, const int* in_sizes, int n_in,
                              void* d_out, int out_size, void* d_ws, size_t ws_size,
                              hipStream_t stream) {
    const float* x     = (const float*)d_in[0];
    const float* W_ih  = (const float*)d_in[1];
    const float* W_hh  = (const float*)d_in[2];
    const float* b_ih  = (const float*)d_in[3];
    const float* b_hh  = (const float*)d_in[4];
    const float* W_out = (const float*)d_in[5];
    const float* b_out = (const float*)d_in[6];
    float* out = (float*)d_out;

    dim3 grid(GRID), block(NTHR);
    flowlstm<<<grid, block, 0, stream>>>(x, W_ih, W_hh, b_ih, b_hh, W_out, b_out, out);
}

// Round 8
// 170.508 us; speedup vs baseline: 2.1069x; 1.1171x over previous
//
#include <hip/hip_runtime.h>

#define I_DIM 17
#define H_DIM 128
#define T_DIM 19
#define B_DIM 32768
#define M_ROWS 128
#define NTHR 512
#define GRID (B_DIM / M_ROWS) /* 256 = one block per CU, ONE pass */
#define XI 323                /* T*I */
#define NF (M_ROWS * XI)      /* 41344 floats per block */
#define XSLOT 4352            /* per-t x slot: 8 rowgrp x 512B (k0..15 frags) + 256B k16 plane */

/* LDS: H dbuf first (16-bit ds imm covers buf+rowgrp selects), then x slots */
#define OFF_H 0               /* 2 x 32768 */
#define OFF_X 65536           /* 19 x 4352 = 82688 */
#define LDS_TOT 148224

typedef __bf16 bf16x8 __attribute__((ext_vector_type(8)));
typedef float f32x4 __attribute__((ext_vector_type(4)));
union FragU { bf16x8 v; unsigned short s[8]; uint4 u; };

#define K1 1.4426950408889634f
#define K2 2.8853900817779268f

__device__ __forceinline__ unsigned short f2bf(float f) {
    union { float f; unsigned u; } x; x.f = f;
    return (unsigned short)((x.u + 0x8000u) >> 16);
}

/* one 64-row half of one timestep; T_ runtime t; P_, HF_ compile-time */
#define HALF_BODY(T_, P_, HF_, YPT_) do {                                         \
    f32x4 acc[4][4];                                                              \
    _Pragma("unroll") for (int mtl = 0; mtl < 4; ++mtl)                           \
        _Pragma("unroll") for (int g = 0; g < 4; ++g)                             \
            acc[mtl][g] = (f32x4){bias[g], bias[g], bias[g], bias[g]};            \
    /* x-projection: A-frag k0..15 from frag slots, k16 from plane, k17..31 zero */\
    _Pragma("unroll") for (int mtl = 0; mtl < 4; ++mtl) {                         \
        FragU fx; fx.u = (uint4){0u, 0u, 0u, 0u};                                 \
        if (q < 2)                                                                \
            fx.v = *(const bf16x8*)(smem + xyA + ((HF_) * 4 + mtl) * 512);        \
        else if (q == 2)                                                          \
            fx.s[0] = *(const unsigned short*)(smem + xk16 + ((HF_) * 4 + mtl) * 32); \
        _Pragma("unroll") for (int g = 0; g < 4; ++g)                             \
            acc[mtl][g] = __builtin_amdgcn_mfma_f32_16x16x32_bf16(fx.v, wihr[g], acc[mtl][g], 0, 0, 0); \
    }                                                                             \
    /* recurrent: h_{t-1} @ W_hh^T (B-frags in registers) */                      \
    _Pragma("unroll") for (int kk = 0; kk < 4; ++kk)                              \
        _Pragma("unroll") for (int mtl = 0; mtl < 4; ++mtl) {                     \
            bf16x8 a = *(const bf16x8*)(smem + vkk[kk] + ((1 - (P_)) * 32768 + ((HF_) * 4 + mtl) * 4096)); \
            _Pragma("unroll") for (int g = 0; g < 4; ++g)                         \
                acc[mtl][g] = __builtin_amdgcn_mfma_f32_16x16x32_bf16(a, whh[kk][g], acc[mtl][g], 0, 0, 0); \
        }                                                                         \
    /* y_{t-1} = h_{t-1} @ W_out^T, direct to global */                           \
    if ((T_) > 0) {                                                               \
        f32x4 ya = {0.f, 0.f, 0.f, 0.f};                                          \
        _Pragma("unroll") for (int kk = 0; kk < 4; ++kk) {                        \
            bf16x8 a = *(const bf16x8*)(smem + vkk[kk] + vyk + ((1 - (P_)) * 32768 + (HF_) * 16384)); \
            ya = __builtin_amdgcn_mfma_f32_16x16x32_bf16(a, wor[kk], ya, 0, 0, 0);\
        }                                                                         \
        if (yok) {                                                                \
            _Pragma("unroll") for (int r = 0; r < 4; ++r)                         \
                YPT_[r * XI] = ya[r] + ybo;                                       \
        }                                                                         \
        YPT_ += I_DIM;                                                            \
    }                                                                             \
    /* elementwise cell update (5 exp2 + 2 rcp), h_t -> H[P_] */                  \
    _Pragma("unroll") for (int mtl = 0; mtl < 4; ++mtl)                           \
        _Pragma("unroll") for (int r = 0; r < 4; ++r) {                           \
            float ig = acc[mtl][0][r], fg = acc[mtl][1][r];                       \
            float gg = acc[mtl][2][r], og = acc[mtl][3][r];                       \
            float ui = __builtin_amdgcn_exp2f(-K1 * ig);                          \
            float uf = __builtin_amdgcn_exp2f(-K1 * fg);                          \
            float vg = __builtin_amdgcn_exp2f(-K2 * gg);                          \
            float uo = __builtin_amdgcn_exp2f(-K1 * og);                          \
            float A_ = 1.f + ui, F_ = 1.f + uf, G_ = 1.f + vg;                    \
            float AG = A_ * G_;                                                   \
            float c = (cst[(HF_) * 16 + mtl * 4 + r] * AG + (1.f - vg) * F_) * __builtin_amdgcn_rcpf(F_ * AG); \
            cst[(HF_) * 16 + mtl * 4 + r] = c;                                    \
            float vc = __builtin_amdgcn_exp2f(-K2 * c);                           \
            float h = (1.f - vc) * __builtin_amdgcn_rcpf((1.f + uo) * (1.f + vc));\
            *(unsigned short*)(smem + vwr[r] + ((P_) * 32768 + ((HF_) * 4 + mtl) * 4096)) = f2bf(h); \
        }                                                                         \
} while (0)

#define STEP(T_, P_) do {                  \
    HALF_BODY(T_, P_, 0, ypt0);            \
    HALF_BODY(T_, P_, 1, ypt1);            \
    xyA += XSLOT; xk16 += XSLOT;           \
    __syncthreads();                       \
} while (0)

__global__ __launch_bounds__(NTHR)
__attribute__((amdgpu_waves_per_eu(2, 2)))
void flowlstm(
    const float* __restrict__ x, const float* __restrict__ W_ih,
    const float* __restrict__ W_hh, const float* __restrict__ b_ih,
    const float* __restrict__ b_hh, const float* __restrict__ W_out,
    const float* __restrict__ b_out, float* __restrict__ out)
{
    __shared__ __align__(16) unsigned char smem[LDS_TOT];
    const int tid = threadIdx.x;
    const int w = tid >> 6, lane = tid & 63, l15 = lane & 15, q = lane >> 4;
    const int cg = w;                      /* wave owns gate-cols g*128 + cg*16 + l15 */
    const int b0 = blockIdx.x * M_ROWS;

    /* ---- zero H[1] (h_{-1} = 0): 8192 dwords ---- */
    #pragma unroll
    for (int j = 0; j < 16; ++j)
        *(unsigned*)(smem + 32768 + (unsigned)(tid + j * NTHR) * 4) = 0u;

    /* ---- bulk x stage: coalesced dwords -> bf16 frag slots (k<16) + k16 plane ---- */
    {
        const float* xb = x + (size_t)b0 * XI;
        for (int j = 0; j < 81; ++j) {
            int f = tid + j * NTHR;
            if (f < NF) {
                float v = xb[f];
                unsigned uf_ = (unsigned)f;
                unsigned row = (uf_ * 51943u) >> 24;      /* f / 323 */
                unsigned s = uf_ - row * 323u;
                unsigned t = (s * 61681u) >> 20;          /* s / 17 */
                unsigned k = s - t * 17u;
                unsigned a;
                if (k == 16) a = OFF_X + t * XSLOT + 4096 + row * 2;
                else a = OFF_X + t * XSLOT + (row >> 4) * 512 + (k >> 3) * 256
                       + (row & 15) * 16 + (k & 7) * 2;
                *(unsigned short*)(smem + a) = f2bf(v);
            }
        }
    }
    /* ---- W_hh fragments in registers (16 frags = 64 regs) ---- */
    bf16x8 whh[4][4];
    #pragma unroll
    for (int kk = 0; kk < 4; ++kk)
        #pragma unroll
        for (int g = 0; g < 4; ++g) {
            int n = g * H_DIM + cg * 16 + l15;
            const float* s = W_hh + n * H_DIM + kk * 32 + q * 8;
            FragU fu;
            #pragma unroll
            for (int e = 0; e < 8; ++e) fu.s[e] = f2bf(s[e]);
            whh[kk][g] = fu.v;
        }
    /* ---- W_ih fragments in registers (K pad 17->32) ---- */
    bf16x8 wihr[4];
    #pragma unroll
    for (int g = 0; g < 4; ++g) {
        int n = g * H_DIM + cg * 16 + l15;
        FragU fu;
        #pragma unroll
        for (int e = 0; e < 8; ++e) {
            int k = q * 8 + e;
            fu.s[e] = (k < I_DIM) ? f2bf(W_ih[n * I_DIM + k]) : (unsigned short)0;
        }
        wihr[g] = fu.v;
    }
    /* ---- W_out fragments in registers (N pad 17->32) ---- */
    const int ymt = w >> 1, yct = w & 1;
    const int ycol = yct * 16 + l15;
    bf16x8 wor[4];
    #pragma unroll
    for (int kk = 0; kk < 4; ++kk) {
        FragU fu;
        #pragma unroll
        for (int e = 0; e < 8; ++e)
            fu.s[e] = (ycol < I_DIM) ? f2bf(W_out[ycol * H_DIM + kk * 32 + q * 8 + e])
                                     : (unsigned short)0;
        wor[kk] = fu.v;
    }
    float bias[4];
    #pragma unroll
    for (int g = 0; g < 4; ++g) {
        int col = g * H_DIM + cg * 16 + l15;
        bias[g] = b_ih[col] + b_hh[col];
    }
    /* ---- t-invariant LDS vaddrs ---- */
    const unsigned xr7 = (unsigned)((l15 & 7) << 4);
    unsigned vkk[4], vwr[4];
    #pragma unroll
    for (int kk = 0; kk < 4; ++kk)
        vkk[kk] = (unsigned)(l15 * 256 + ((kk * 64 + q * 16) ^ xr7));
    const int colh2 = (cg * 16 + l15) * 2;
    #pragma unroll
    for (int r = 0; r < 4; ++r) {
        int rq = q * 4 + r;
        vwr[r] = (unsigned)(rq * 256 + (colh2 ^ ((rq & 7) << 4)));
    }
    const unsigned vyk = (unsigned)(ymt * 4096);
    const bool yok = (ycol < I_DIM);
    const float ybo = b_out[ycol < I_DIM ? ycol : 16];
    unsigned xyA  = (unsigned)(OFF_X + (q < 2 ? q * 256 : 0) + l15 * 16);
    unsigned xk16 = (unsigned)(OFF_X + 4096 + l15 * 2);
    float* ypt0 = out + (size_t)(b0 + ymt * 16 + q * 4) * XI + ycol;
    float* ypt1 = ypt0 + (size_t)64 * XI;

    float cst[32];
    #pragma unroll
    for (int i = 0; i < 32; ++i) cst[i] = 0.f;

    __syncthreads();   /* staging + zeros visible */

    #pragma unroll 1
    for (int t = 0; t < T_DIM - 1; t += 2) {
        STEP(t, 0);
        STEP(t + 1, 1);
    }
    STEP(T_DIM - 1, 0);   /* t = 18, writes H[0] */

    /* ---- epilogue: y_18 from H[0] (both halves) ---- */
    {
        f32x4 ya = {0.f, 0.f, 0.f, 0.f};
        #pragma unroll
        for (int kk = 0; kk < 4; ++kk) {
            bf16x8 a = *(const bf16x8*)(smem + vkk[kk] + vyk);
            ya = __builtin_amdgcn_mfma_f32_16x16x32_bf16(a, wor[kk], ya, 0, 0, 0);
        }
        if (yok) {
            #pragma unroll
            for (int r = 0; r < 4; ++r)
                ypt0[r * XI] = ya[r] + ybo;
        }
    }
    {
        f32x4 ya = {0.f, 0.f, 0.f, 0.f};
        #pragma unroll
        for (int kk = 0; kk < 4; ++kk) {
            bf16x8 a = *(const bf16x8*)(smem + vkk[kk] + vyk + 16384);
            ya = __builtin_amdgcn_mfma_f32_16x16x32_bf16(a, wor[kk], ya, 0, 0, 0);
        }
        if (yok) {
            #pragma unroll
            for (int r = 0; r < 4; ++r)
                ypt1[r * XI] = ya[r] + ybo;
        }
    }
}

extern "C" void kernel_launch(void* const* d_in, const int* in_sizes, int n_in,
                              void* d_out, int out_size, void* d_ws, size_t ws_size,
                              hipStream_t stream) {
    const float* x     = (const float*)d_in[0];
    const float* W_ih  = (const float*)d_in[1];
    const float* W_hh  = (const float*)d_in[2];
    const float* b_ih  = (const float*)d_in[3];
    const float* b_hh  = (const float*)d_in[4];
    const float* W_out = (const float*)d_in[5];
    const float* b_out = (const float*)d_in[6];
    float* out = (float*)d_out;

    dim3 grid(GRID), block(NTHR);
    flowlstm<<<grid, block, 0, stream>>>(x, W_ih, W_hh, b_ih, b_hh, W_out, b_out, out);
}

// Round 9
// 160.485 us; speedup vs baseline: 2.2385x; 1.0625x over previous
//
#include <hip/hip_runtime.h>

#define I_DIM 17
#define H_DIM 128
#define T_DIM 19
#define B_DIM 32768
#define M_ROWS 128
#define NTHR 512
#define GRID (B_DIM / M_ROWS) /* 256 = one block per CU, ONE pass */
#define XI 323                /* T*I */
#define NF (M_ROWS * XI)      /* 41344 floats per block */
#define XSLOT 4352            /* per-t x slot: 8 rowgrp x 512B (k0..15) + 256B k16 plane */

#define OFF_H 0               /* 2 x 32768 */
#define OFF_X 65536           /* 19 x 4352 = 82688 */
#define LDS_TOT 148224

typedef __bf16 bf16x8 __attribute__((ext_vector_type(8)));
typedef float f32x4 __attribute__((ext_vector_type(4)));
union FragU { bf16x8 v; unsigned short s[8]; uint4 u; };

#define K1 1.4426950408889634f
#define K2 2.8853900817779268f

__device__ __forceinline__ unsigned short f2bf(float f) {
    union { float f; unsigned u; } x; x.f = f;
    return (unsigned short)((x.u + 0x8000u) >> 16);
}

/* ---- quarter macros: QT_ in 0..3 covers rows QT_*32..+31 (mtl = QT_*2+m2) ---- */

/* gates MFMA for one quarter into ACC_ (bias pre-scaled; x-proj always; recurrent if REC_) */
#define MFMA_Q(P_, QT_, ACC_, REC_) do {                                          \
    _Pragma("unroll") for (int m2 = 0; m2 < 2; ++m2) {                            \
        _Pragma("unroll") for (int g = 0; g < 4; ++g)                             \
            ACC_[m2][g] = (f32x4){bias[g], bias[g], bias[g], bias[g]};            \
        FragU fx; fx.u = (uint4){0u, 0u, 0u, 0u};                                 \
        if (q < 2)                                                                \
            fx.v = *(const bf16x8*)(smem + xyA + ((QT_) * 2 + m2) * 512);         \
        else if (q == 2)                                                          \
            fx.s[0] = *(const unsigned short*)(smem + xk16 + ((QT_) * 2 + m2) * 32); \
        _Pragma("unroll") for (int g = 0; g < 4; ++g)                             \
            ACC_[m2][g] = __builtin_amdgcn_mfma_f32_16x16x32_bf16(fx.v, wihr[g], ACC_[m2][g], 0, 0, 0); \
    }                                                                             \
    if (REC_) {                                                                   \
        _Pragma("unroll") for (int kk = 0; kk < 4; ++kk)                          \
            _Pragma("unroll") for (int m2 = 0; m2 < 2; ++m2) {                    \
                bf16x8 a = *(const bf16x8*)(smem + vkk[kk] + ((1 - (P_)) * 32768 + ((QT_) * 2 + m2) * 4096)); \
                _Pragma("unroll") for (int g = 0; g < 4; ++g)                     \
                    ACC_[m2][g] = __builtin_amdgcn_mfma_f32_16x16x32_bf16(a, whh[kk][g], ACC_[m2][g], 0, 0, 0); \
            }                                                                     \
    }                                                                             \
} while (0)

/* elementwise + h-write for one quarter (gates arrive pre-scaled by -K1/-K2) */
#define ELEM_Q(P_, QT_, ACC_) do {                                                \
    _Pragma("unroll") for (int m2 = 0; m2 < 2; ++m2)                              \
        _Pragma("unroll") for (int r = 0; r < 4; ++r) {                           \
            float ui = __builtin_amdgcn_exp2f(ACC_[m2][0][r]);                    \
            float uf = __builtin_amdgcn_exp2f(ACC_[m2][1][r]);                    \
            float vg = __builtin_amdgcn_exp2f(ACC_[m2][2][r]);                    \
            float uo = __builtin_amdgcn_exp2f(ACC_[m2][3][r]);                    \
            float A_ = 1.f + ui, F_ = 1.f + uf, G_ = 1.f + vg;                    \
            float AG = A_ * G_;                                                   \
            int ci = (QT_) * 8 + m2 * 4 + r;                                      \
            float c = (cst[ci] * AG + (1.f - vg) * F_) * __builtin_amdgcn_rcpf(F_ * AG); \
            cst[ci] = c;                                                          \
            float vc = __builtin_amdgcn_exp2f(-K2 * c);                           \
            float h = (1.f - vc) * __builtin_amdgcn_rcpf((1.f + uo) * (1.f + vc));\
            *(unsigned short*)(smem + vwr[r] + ((P_) * 32768 + ((QT_) * 2 + m2) * 4096)) = f2bf(h); \
        }                                                                         \
} while (0)

/* y_{t-1} from H[1-P]: each wave one 16-row tile per 64-row half */
#define Y_BURST(P_) do {                                                          \
    f32x4 ya0 = {0.f, 0.f, 0.f, 0.f}, ya1 = {0.f, 0.f, 0.f, 0.f};                 \
    _Pragma("unroll") for (int kk = 0; kk < 4; ++kk) {                            \
        bf16x8 a0 = *(const bf16x8*)(smem + vkk[kk] + vyk + (1 - (P_)) * 32768);  \
        bf16x8 a1 = *(const bf16x8*)(smem + vkk[kk] + vyk + (1 - (P_)) * 32768 + 16384); \
        ya0 = __builtin_amdgcn_mfma_f32_16x16x32_bf16(a0, wor[kk], ya0, 0, 0, 0); \
        ya1 = __builtin_amdgcn_mfma_f32_16x16x32_bf16(a1, wor[kk], ya1, 0, 0, 0); \
    }                                                                             \
    if (yok) {                                                                    \
        _Pragma("unroll") for (int r = 0; r < 4; ++r) {                           \
            ypt0[r * XI] = ya0[r] + ybo;                                          \
            ypt1[r * XI] = ya1[r] + ybo;                                          \
        }                                                                         \
    }                                                                             \
    ypt0 += I_DIM; ypt1 += I_DIM;                                                 \
} while (0)

/* full step with quarter ping-pong pipeline; P_ = t&1; writes H[P_], reads H[1-P_] */
#define STEP(P_) do {                      \
    MFMA_Q(P_, 0, accA, 1);                \
    MFMA_Q(P_, 1, accB, 1);                \
    ELEM_Q(P_, 0, accA);                   \
    MFMA_Q(P_, 2, accA, 1);                \
    ELEM_Q(P_, 1, accB);                   \
    MFMA_Q(P_, 3, accB, 1);                \
    ELEM_Q(P_, 2, accA);                   \
    Y_BURST(P_);                           \
    ELEM_Q(P_, 3, accB);                   \
    xyA += XSLOT; xk16 += XSLOT;           \
    __syncthreads();                       \
} while (0)

__global__ __launch_bounds__(NTHR)
__attribute__((amdgpu_waves_per_eu(2, 2)))
void flowlstm(
    const float* __restrict__ x, const float* __restrict__ W_ih,
    const float* __restrict__ W_hh, const float* __restrict__ b_ih,
    const float* __restrict__ b_hh, const float* __restrict__ W_out,
    const float* __restrict__ b_out, float* __restrict__ out)
{
    __shared__ __align__(16) unsigned char smem[LDS_TOT];
    const int tid = threadIdx.x;
    const int w = tid >> 6, lane = tid & 63, l15 = lane & 15, q = lane >> 4;
    const int cg = w;                      /* wave owns gate-cols g*128 + cg*16 + l15 */
    const int b0 = blockIdx.x * M_ROWS;

    /* ---- bulk x stage: coalesced dwords -> bf16 frag slots (k<16) + k16 plane ---- */
    {
        const float* xb = x + (size_t)b0 * XI;
        for (int j = 0; j < 81; ++j) {
            int f = tid + j * NTHR;
            if (f < NF) {
                float v = xb[f];
                unsigned uf_ = (unsigned)f;
                unsigned row = (uf_ * 51943u) >> 24;      /* f / 323 */
                unsigned s = uf_ - row * 323u;
                unsigned t = (s * 61681u) >> 20;          /* s / 17 */
                unsigned k = s - t * 17u;
                unsigned a;
                if (k == 16) a = OFF_X + t * XSLOT + 4096 + row * 2;
                else a = OFF_X + t * XSLOT + (row >> 4) * 512 + (k >> 3) * 256
                       + (row & 15) * 16 + (k & 7) * 2;
                *(unsigned short*)(smem + a) = f2bf(v);
            }
        }
    }
    /* gate scale: i,f,o -> -K1 ; g -> -K2 (folds sigmoid/tanh arg scaling into weights) */
    float gsc[4] = { -K1, -K1, -K2, -K1 };

    /* ---- W_hh fragments in registers, PRE-SCALED (16 frags = 64 regs) ---- */
    bf16x8 whh[4][4];
    #pragma unroll
    for (int kk = 0; kk < 4; ++kk)
        #pragma unroll
        for (int g = 0; g < 4; ++g) {
            int n = g * H_DIM + cg * 16 + l15;
            const float* s = W_hh + n * H_DIM + kk * 32 + q * 8;
            FragU fu;
            #pragma unroll
            for (int e = 0; e < 8; ++e) fu.s[e] = f2bf(s[e] * gsc[g]);
            whh[kk][g] = fu.v;
        }
    /* ---- W_ih fragments in registers, PRE-SCALED (K pad 17->32) ---- */
    bf16x8 wihr[4];
    #pragma unroll
    for (int g = 0; g < 4; ++g) {
        int n = g * H_DIM + cg * 16 + l15;
        FragU fu;
        #pragma unroll
        for (int e = 0; e < 8; ++e) {
            int k = q * 8 + e;
            fu.s[e] = (k < I_DIM) ? f2bf(W_ih[n * I_DIM + k] * gsc[g]) : (unsigned short)0;
        }
        wihr[g] = fu.v;
    }
    /* ---- W_out fragments in registers (N pad 17->32) ---- */
    const int ymt = w >> 1, yct = w & 1;
    const int ycol = yct * 16 + l15;
    bf16x8 wor[4];
    #pragma unroll
    for (int kk = 0; kk < 4; ++kk) {
        FragU fu;
        #pragma unroll
        for (int e = 0; e < 8; ++e)
            fu.s[e] = (ycol < I_DIM) ? f2bf(W_out[ycol * H_DIM + kk * 32 + q * 8 + e])
                                     : (unsigned short)0;
        wor[kk] = fu.v;
    }
    float bias[4];
    #pragma unroll
    for (int g = 0; g < 4; ++g) {
        int col = g * H_DIM + cg * 16 + l15;
        bias[g] = (b_ih[col] + b_hh[col]) * gsc[g];
    }
    /* ---- t-invariant LDS vaddrs ---- */
    const unsigned xr7 = (unsigned)((l15 & 7) << 4);
    unsigned vkk[4], vwr[4];
    #pragma unroll
    for (int kk = 0; kk < 4; ++kk)
        vkk[kk] = (unsigned)(l15 * 256 + ((kk * 64 + q * 16) ^ xr7));
    const int colh2 = (cg * 16 + l15) * 2;
    #pragma unroll
    for (int r = 0; r < 4; ++r) {
        int rq = q * 4 + r;
        vwr[r] = (unsigned)(rq * 256 + (colh2 ^ ((rq & 7) << 4)));
    }
    const unsigned vyk = (unsigned)(ymt * 4096);
    const bool yok = (ycol < I_DIM);
    const float ybo = b_out[ycol < I_DIM ? ycol : 16];
    unsigned xyA  = (unsigned)(OFF_X + (q < 2 ? q * 256 : 0) + l15 * 16);
    unsigned xk16 = (unsigned)(OFF_X + 4096 + l15 * 2);
    float* ypt0 = out + (size_t)(b0 + ymt * 16 + q * 4) * XI + ycol;
    float* ypt1 = ypt0 + (size_t)64 * XI;

    float cst[32];
    #pragma unroll
    for (int i = 0; i < 32; ++i) cst[i] = 0.f;

    f32x4 accA[2][4], accB[2][4];

    __syncthreads();   /* x staging visible */

    /* ---- peeled t=0: no recurrent GEMM, no y; writes H[0] ---- */
    MFMA_Q(0, 0, accA, 0);
    MFMA_Q(0, 1, accB, 0);
    ELEM_Q(0, 0, accA);
    MFMA_Q(0, 2, accA, 0);
    ELEM_Q(0, 1, accB);
    MFMA_Q(0, 3, accB, 0);
    ELEM_Q(0, 2, accA);
    ELEM_Q(0, 3, accB);
    xyA += XSLOT; xk16 += XSLOT;
    __syncthreads();

    /* ---- t = 1..18 ---- */
    #pragma unroll 1
    for (int t = 1; t < T_DIM; t += 2) {
        STEP(1);
        STEP(0);
    }

    /* ---- epilogue: y_18 from H[0] ---- */
    {
        f32x4 ya0 = {0.f, 0.f, 0.f, 0.f}, ya1 = {0.f, 0.f, 0.f, 0.f};
        #pragma unroll
        for (int kk = 0; kk < 4; ++kk) {
            bf16x8 a0 = *(const bf16x8*)(smem + vkk[kk] + vyk);
            bf16x8 a1 = *(const bf16x8*)(smem + vkk[kk] + vyk + 16384);
            ya0 = __builtin_amdgcn_mfma_f32_16x16x32_bf16(a0, wor[kk], ya0, 0, 0, 0);
            ya1 = __builtin_amdgcn_mfma_f32_16x16x32_bf16(a1, wor[kk], ya1, 0, 0, 0);
        }
        if (yok) {
            #pragma unroll
            for (int r = 0; r < 4; ++r) {
                ypt0[r * XI] = ya0[r] + ybo;
                ypt1[r * XI] = ya1[r] + ybo;
            }
        }
    }
}

extern "C" void kernel_launch(void* const* d_in, const int* in_sizes, int n_in,
                              void* d_out, int out_size, void* d_ws, size_t ws_size,
                              hipStream_t stream) {
    const float* x     = (const float*)d_in[0];
    const float* W_ih  = (const float*)d_in[1];
    const float* W_hh  = (const float*)d_in[2];
    const float* b_ih  = (const float*)d_in[3];
    const float* b_hh  = (const float*)d_in[4];
    const float* W_out = (const float*)d_in[5];
    const float* b_out = (const float*)d_in[6];
    float* out = (float*)d_out;

    dim3 grid(GRID), block(NTHR);
    flowlstm<<<grid, block, 0, stream>>>(x, W_ih, W_hh, b_ih, b_hh, W_out, b_out, out);
}

// Round 10
// 149.292 us; speedup vs baseline: 2.4063x; 1.0750x over previous
//
#include <hip/hip_runtime.h>

#define I_DIM 17
#define H_DIM 128
#define T_DIM 19
#define B_DIM 32768
#define M_ROWS 128
#define NTHR 512
#define GRID (B_DIM / M_ROWS) /* 256 = one block per CU, ONE pass */
#define XI 323                /* T*I */
#define NF (M_ROWS * XI)      /* 41344 floats per block */
#define XSLOT 4352            /* per-t x slot: 8 rowgrp x 512B (k0..15) + 256B k16 plane */

#define OFF_H 0               /* 2 x 32768 */
#define OFF_X 65536           /* 19 x 4352 = 82688 */
#define OFF_WO 148224         /* 8 frags x 1024 = 8192 */
#define LDS_TOT 156416

typedef __bf16 bf16x8 __attribute__((ext_vector_type(8)));
typedef float f32x4 __attribute__((ext_vector_type(4)));
union FragU { bf16x8 v; unsigned short s[8]; uint4 u; };

#define K1 1.4426950408889634f
#define K2 2.8853900817779268f

__device__ __forceinline__ unsigned short f2bf(float f) {
    union { float f; unsigned u; } x; x.f = f;
    return (unsigned short)((x.u + 0x8000u) >> 16);
}

/* barrier that drains LDS only — global y-stores stay in flight (T4: never vmcnt(0) in loop) */
#define SYNC_LDS() do {                                        \
    asm volatile("s_waitcnt lgkmcnt(0)" ::: "memory");         \
    __builtin_amdgcn_s_barrier();                              \
} while (0)

/* gates MFMA for one quarter into ACC_ (bias pre-scaled; x-proj always; recurrent if REC_) */
#define MFMA_Q(P_, QT_, ACC_, REC_) do {                                          \
    _Pragma("unroll") for (int m2 = 0; m2 < 2; ++m2) {                            \
        _Pragma("unroll") for (int g = 0; g < 4; ++g)                             \
            ACC_[m2][g] = (f32x4){bias[g], bias[g], bias[g], bias[g]};            \
        FragU fx; fx.u = (uint4){0u, 0u, 0u, 0u};                                 \
        if (q < 2)                                                                \
            fx.v = *(const bf16x8*)(smem + xyA + ((QT_) * 2 + m2) * 512);         \
        else if (q == 2)                                                          \
            fx.s[0] = *(const unsigned short*)(smem + xk16 + ((QT_) * 2 + m2) * 32); \
        _Pragma("unroll") for (int g = 0; g < 4; ++g)                             \
            ACC_[m2][g] = __builtin_amdgcn_mfma_f32_16x16x32_bf16(fx.v, wihr[g], ACC_[m2][g], 0, 0, 0); \
    }                                                                             \
    if (REC_) {                                                                   \
        _Pragma("unroll") for (int kk = 0; kk < 4; ++kk)                          \
            _Pragma("unroll") for (int m2 = 0; m2 < 2; ++m2) {                    \
                bf16x8 a = *(const bf16x8*)(smem + vkk[kk] + ((1 - (P_)) * 32768 + ((QT_) * 2 + m2) * 4096)); \
                _Pragma("unroll") for (int g = 0; g < 4; ++g)                     \
                    ACC_[m2][g] = __builtin_amdgcn_mfma_f32_16x16x32_bf16(a, whh[kk][g], ACC_[m2][g], 0, 0, 0); \
            }                                                                     \
    }                                                                             \
} while (0)

/* elementwise + h-write for one quarter (gates arrive pre-scaled by -K1/-K2) */
#define ELEM_Q(P_, QT_, ACC_) do {                                                \
    _Pragma("unroll") for (int m2 = 0; m2 < 2; ++m2)                              \
        _Pragma("unroll") for (int r = 0; r < 4; ++r) {                           \
            float ui = __builtin_amdgcn_exp2f(ACC_[m2][0][r]);                    \
            float uf = __builtin_amdgcn_exp2f(ACC_[m2][1][r]);                    \
            float vg = __builtin_amdgcn_exp2f(ACC_[m2][2][r]);                    \
            float uo = __builtin_amdgcn_exp2f(ACC_[m2][3][r]);                    \
            float A_ = 1.f + ui, F_ = 1.f + uf, G_ = 1.f + vg;                    \
            float AG = A_ * G_;                                                   \
            int ci = (QT_) * 8 + m2 * 4 + r;                                      \
            float c = (cst[ci] * AG + (1.f - vg) * F_) * __builtin_amdgcn_rcpf(F_ * AG); \
            cst[ci] = c;                                                          \
            float vc = __builtin_amdgcn_exp2f(-K2 * c);                           \
            float h = (1.f - vc) * __builtin_amdgcn_rcpf((1.f + uo) * (1.f + vc));\
            *(unsigned short*)(smem + vwr[r] + ((P_) * 32768 + ((QT_) * 2 + m2) * 4096)) = f2bf(h); \
        }                                                                         \
} while (0)

/* y_{t-1} from H[1-P]: each wave one 16-row tile per 64-row half; wor from LDS */
#define Y_BURST(P_) do {                                                          \
    f32x4 ya0 = {0.f, 0.f, 0.f, 0.f}, ya1 = {0.f, 0.f, 0.f, 0.f};                 \
    _Pragma("unroll") for (int kk = 0; kk < 4; ++kk) {                            \
        bf16x8 b  = *(const bf16x8*)(smem + vwo + kk * 1024);                     \
        bf16x8 a0 = *(const bf16x8*)(smem + vkk[kk] + vyk + (1 - (P_)) * 32768);  \
        bf16x8 a1 = *(const bf16x8*)(smem + vkk[kk] + vyk + (1 - (P_)) * 32768 + 16384); \
        ya0 = __builtin_amdgcn_mfma_f32_16x16x32_bf16(a0, b, ya0, 0, 0, 0);       \
        ya1 = __builtin_amdgcn_mfma_f32_16x16x32_bf16(a1, b, ya1, 0, 0, 0);       \
    }                                                                             \
    if (yok) {                                                                    \
        _Pragma("unroll") for (int r = 0; r < 4; ++r) {                           \
            ypt0[r * XI] = ya0[r] + ybo;                                          \
            ypt1[r * XI] = ya1[r] + ybo;                                          \
        }                                                                         \
    }                                                                             \
    ypt0 += I_DIM; ypt1 += I_DIM;                                                 \
} while (0)

/* full step, quarter ping-pong pipeline; P_ = t&1; writes H[P_], reads H[1-P_] */
#define STEP(P_) do {                      \
    MFMA_Q(P_, 0, accA, 1);                \
    MFMA_Q(P_, 1, accB, 1);                \
    ELEM_Q(P_, 0, accA);                   \
    MFMA_Q(P_, 2, accA, 1);                \
    ELEM_Q(P_, 1, accB);                   \
    MFMA_Q(P_, 3, accB, 1);                \
    ELEM_Q(P_, 2, accA);                   \
    Y_BURST(P_);                           \
    ELEM_Q(P_, 3, accB);                   \
    xyA += XSLOT; xk16 += XSLOT;           \
    SYNC_LDS();                            \
} while (0)

__global__ __launch_bounds__(NTHR)
__attribute__((amdgpu_waves_per_eu(2, 2)))
void flowlstm(
    const float* __restrict__ x, const float* __restrict__ W_ih,
    const float* __restrict__ W_hh, const float* __restrict__ b_ih,
    const float* __restrict__ b_hh, const float* __restrict__ W_out,
    const float* __restrict__ b_out, float* __restrict__ out)
{
    __shared__ __align__(16) unsigned char smem[LDS_TOT];
    const int tid = threadIdx.x;
    const int w = tid >> 6, lane = tid & 63, l15 = lane & 15, q = lane >> 4;
    const int cg = w;                      /* wave owns gate-cols g*128 + cg*16 + l15 */
    const int b0 = blockIdx.x * M_ROWS;

    /* ---- bulk x stage: coalesced dwords -> bf16 frag slots (k<16) + k16 plane ---- */
    {
        const float* xb = x + (size_t)b0 * XI;
        for (int j = 0; j < 81; ++j) {
            int f = tid + j * NTHR;
            if (f < NF) {
                float v = xb[f];
                unsigned uf_ = (unsigned)f;
                unsigned row = (uf_ * 51943u) >> 24;      /* f / 323 */
                unsigned s = uf_ - row * 323u;
                unsigned t = (s * 61681u) >> 20;          /* s / 17 */
                unsigned k = s - t * 17u;
                unsigned a;
                if (k == 16) a = OFF_X + t * XSLOT + 4096 + row * 2;
                else a = OFF_X + t * XSLOT + (row >> 4) * 512 + (k >> 3) * 256
                       + (row & 15) * 16 + (k & 7) * 2;
                *(unsigned short*)(smem + a) = f2bf(v);
            }
        }
    }
    /* ---- W_out fragments -> LDS (8 frags = yct*4+kk, N pad 17->32) ---- */
    {
        int ln = tid & 63, f = tid >> 6;
        int kk = f & 3, ct = f >> 2;
        int o = ct * 16 + (ln & 15);
        int kb = kk * 32 + (ln >> 4) * 8;
        FragU fu;
        #pragma unroll
        for (int e = 0; e < 8; ++e)
            fu.s[e] = (o < I_DIM) ? f2bf(W_out[o * H_DIM + kb + e]) : (unsigned short)0;
        *(uint4*)(smem + OFF_WO + f * 1024 + ln * 16) = fu.u;
    }
    /* gate scale: i,f,o -> -K1 ; g -> -K2 (folds activation arg scaling into weights) */
    float gsc[4] = { -K1, -K1, -K2, -K1 };

    /* ---- W_hh fragments in registers, PRE-SCALED (16 frags = 64 regs) ---- */
    bf16x8 whh[4][4];
    #pragma unroll
    for (int kk = 0; kk < 4; ++kk)
        #pragma unroll
        for (int g = 0; g < 4; ++g) {
            int n = g * H_DIM + cg * 16 + l15;
            const float* s = W_hh + n * H_DIM + kk * 32 + q * 8;
            FragU fu;
            #pragma unroll
            for (int e = 0; e < 8; ++e) fu.s[e] = f2bf(s[e] * gsc[g]);
            whh[kk][g] = fu.v;
        }
    /* ---- W_ih fragments in registers, PRE-SCALED (K pad 17->32) ---- */
    bf16x8 wihr[4];
    #pragma unroll
    for (int g = 0; g < 4; ++g) {
        int n = g * H_DIM + cg * 16 + l15;
        FragU fu;
        #pragma unroll
        for (int e = 0; e < 8; ++e) {
            int k = q * 8 + e;
            fu.s[e] = (k < I_DIM) ? f2bf(W_ih[n * I_DIM + k] * gsc[g]) : (unsigned short)0;
        }
        wihr[g] = fu.v;
    }
    float bias[4];
    #pragma unroll
    for (int g = 0; g < 4; ++g) {
        int col = g * H_DIM + cg * 16 + l15;
        bias[g] = (b_ih[col] + b_hh[col]) * gsc[g];
    }
    /* ---- t-invariant LDS vaddrs ---- */
    const unsigned xr7 = (unsigned)((l15 & 7) << 4);
    unsigned vkk[4], vwr[4];
    #pragma unroll
    for (int kk = 0; kk < 4; ++kk)
        vkk[kk] = (unsigned)(l15 * 256 + ((kk * 64 + q * 16) ^ xr7));
    const int colh2 = (cg * 16 + l15) * 2;
    #pragma unroll
    for (int r = 0; r < 4; ++r) {
        int rq = q * 4 + r;
        vwr[r] = (unsigned)(rq * 256 + (colh2 ^ ((rq & 7) << 4)));
    }
    const int ymt = w >> 1, yct = w & 1;
    const int ycol = yct * 16 + l15;
    const unsigned vyk = (unsigned)(ymt * 4096);
    const unsigned vwo = (unsigned)(OFF_WO + yct * 4096 + lane * 16);
    const bool yok = (ycol < I_DIM);
    const float ybo = b_out[ycol < I_DIM ? ycol : 16];
    unsigned xyA  = (unsigned)(OFF_X + (q < 2 ? q * 256 : 0) + l15 * 16);
    unsigned xk16 = (unsigned)(OFF_X + 4096 + l15 * 2);
    float* ypt0 = out + (size_t)(b0 + ymt * 16 + q * 4) * XI + ycol;
    float* ypt1 = ypt0 + (size_t)64 * XI;

    float cst[32];
    #pragma unroll
    for (int i = 0; i < 32; ++i) cst[i] = 0.f;

    f32x4 accA[2][4], accB[2][4];

    __syncthreads();   /* prologue staging visible (full drain OK here, once) */

    /* ---- peeled t=0: no recurrent GEMM, no y; writes H[0] ---- */
    MFMA_Q(0, 0, accA, 0);
    MFMA_Q(0, 1, accB, 0);
    ELEM_Q(0, 0, accA);
    MFMA_Q(0, 2, accA, 0);
    ELEM_Q(0, 1, accB);
    MFMA_Q(0, 3, accB, 0);
    ELEM_Q(0, 2, accA);
    ELEM_Q(0, 3, accB);
    xyA += XSLOT; xk16 += XSLOT;
    SYNC_LDS();

    /* ---- t = 1..18 ---- */
    #pragma unroll 1
    for (int t = 1; t < T_DIM; t += 2) {
        STEP(1);
        STEP(0);
    }

    /* ---- epilogue: y_18 from H[0] ---- */
    {
        f32x4 ya0 = {0.f, 0.f, 0.f, 0.f}, ya1 = {0.f, 0.f, 0.f, 0.f};
        #pragma unroll
        for (int kk = 0; kk < 4; ++kk) {
            bf16x8 b  = *(const bf16x8*)(smem + vwo + kk * 1024);
            bf16x8 a0 = *(const bf16x8*)(smem + vkk[kk] + vyk);
            bf16x8 a1 = *(const bf16x8*)(smem + vkk[kk] + vyk + 16384);
            ya0 = __builtin_amdgcn_mfma_f32_16x16x32_bf16(a0, b, ya0, 0, 0, 0);
            ya1 = __builtin_amdgcn_mfma_f32_16x16x32_bf16(a1, b, ya1, 0, 0, 0);
        }
        if (yok) {
            #pragma unroll
            for (int r = 0; r < 4; ++r) {
                ypt0[r * XI] = ya0[r] + ybo;
                ypt1[r * XI] = ya1[r] + ybo;
            }
        }
    }
}

extern "C" void kernel_launch(void* const* d_in, const int* in_sizes, int n_in,
                              void* d_out, int out_size, void* d_ws, size_t ws_size,
                              hipStream_t stream) {
    const float* x     = (const float*)d_in[0];
    const float* W_ih  = (const float*)d_in[1];
    const float* W_hh  = (const float*)d_in[2];
    const float* b_ih  = (const float*)d_in[3];
    const float* b_hh  = (const float*)d_in[4];
    const float* W_out = (const float*)d_in[5];
    const float* b_out = (const float*)d_in[6];
    float* out = (float*)d_out;

    dim3 grid(GRID), block(NTHR);
    flowlstm<<<grid, block, 0, stream>>>(x, W_ih, W_hh, b_ih, b_hh, W_out, b_out, out);
}